// Round 6
// baseline (194.612 us; speedup 1.0000x reference)
//
#include <hip/hip_runtime.h>
#include <hip/hip_bf16.h>

#define NB 32
#define NL 100
#define ND 128
#define NH 8
#define NE 64
#define NC 16

// scratch layout (float offsets into g_ws) — round-3 proven layout
#define WS_WXT  0        // 128*128 transposed Wx
#define WS_WFT  16384    // 128*128 transposed ffn_w
#define WS_PROJ 32768    // 8*64 combined att_e @ We
#define WS_XI   33280    // B*L*H dest scores
#define WS_XJ   58880    // B*L*H src scores
#define WS_XP   84480    // B*L*128 projected x (f32)
#define WS_ES   (84480 + NB * NL * ND)          // B*L*L*H edge scores
#define WS_TOT  (WS_ES + NB * NL * NL * NH)

__device__ float g_ws[WS_TOT];

static __device__ __forceinline__ float pick8(const float* a, int c) {
    return (c < 4)
        ? ((c < 2) ? (c == 0 ? a[0] : a[1]) : (c == 2 ? a[2] : a[3]))
        : ((c < 6) ? (c == 4 ? a[4] : a[5]) : (c == 6 ? a[6] : a[7]));
}

// ---------------------------------------------------------------- prep (round-3 exact)
__global__ __launch_bounds__(256) void prep_kernel(
        const float* __restrict__ Wx, const float* __restrict__ We,
        const float* __restrict__ att_e, const float* __restrict__ ffn_w) {
    int gid = blockIdx.x * 256 + threadIdx.x;
    if (gid < 16384) {
        int k = gid >> 7, d = gid & 127;
        g_ws[WS_WXT + gid] = Wx[d * 128 + k];
        g_ws[WS_WFT + gid] = ffn_w[d * 128 + k];
    } else if (gid < 16384 + 512) {
        int pid = gid - 16384;
        int h = pid >> 6, eix = pid & 63;
        float acc = 0.f;
        #pragma unroll
        for (int c = 0; c < NC; ++c)
            acc += att_e[h * NC + c] * We[(h * NC + c) * NE + eix];
        g_ws[WS_PROJ + pid] = acc;
    }
}

// ---------------------------------------------------------------- escore (round-3 exact: 5.67 TB/s measured)
__global__ __launch_bounds__(256) void escore_kernel(const float* __restrict__ e) {
    const float4* proj4 = (const float4*)(g_ws + WS_PROJ);
    int t = threadIdx.x;
    int lane = t & 63;
    int j_sub = lane >> 3, c_sub = lane & 7;
    float4 p4[16];
    #pragma unroll
    for (int h = 0; h < 8; ++h) {
        p4[h * 2]     = proj4[h * 16 + c_sub * 2];
        p4[h * 2 + 1] = proj4[h * 16 + c_sub * 2 + 1];
    }
    const float4* e4 = (const float4*)e;
    int wid = blockIdx.x * 4 + (t >> 6);
    int nw = gridDim.x * 4;
    for (int chunk = wid; chunk < NB * NL * NL / 8; chunk += nw) {
        long rid = (long)chunk * 8 + j_sub;
        float4 ev0 = e4[rid * 16 + c_sub * 2];
        float4 ev1 = e4[rid * 16 + c_sub * 2 + 1];
        float part[8];
        #pragma unroll
        for (int h = 0; h < 8; ++h) {
            float4 a = p4[h * 2], bq = p4[h * 2 + 1];
            part[h] = ev0.x * a.x + ev0.y * a.y + ev0.z * a.z + ev0.w * a.w
                    + ev1.x * bq.x + ev1.y * bq.y + ev1.z * bq.z + ev1.w * bq.w;
        }
        #pragma unroll
        for (int st = 1; st < 8; st <<= 1)
            #pragma unroll
            for (int h = 0; h < 8; ++h)
                part[h] += __shfl_xor(part[h], st);
        g_ws[WS_ES + rid * 8 + c_sub] = pick8(part, c_sub);
    }
}

// ---------------------------------------------------------------- xproj: 4 rows/block (round-5 proven)
__global__ __launch_bounds__(128) void xproj_kernel(
        const float* __restrict__ x,
        const float* __restrict__ att_src, const float* __restrict__ att_dst) {
    __shared__ float xrowL[4][128];
    int bl0 = blockIdx.x * 4;
    int t = threadIdx.x;
    #pragma unroll
    for (int r = 0; r < 4; ++r)
        xrowL[r][t] = x[(bl0 + r) * 128 + t];
    __syncthreads();
    const float* WxT = g_ws + WS_WXT;
    float acc0 = 0.f, acc1 = 0.f, acc2 = 0.f, acc3 = 0.f;
    #pragma unroll 8
    for (int k = 0; k < 128; ++k) {
        float wv = WxT[k * 128 + t];
        acc0 = fmaf(xrowL[0][k], wv, acc0);
        acc1 = fmaf(xrowL[1][k], wv, acc1);
        acc2 = fmaf(xrowL[2][k], wv, acc2);
        acc3 = fmaf(xrowL[3][k], wv, acc3);
    }
    float accs[4] = {acc0, acc1, acc2, acc3};
    float asr = att_src[t], adt = att_dst[t];
    #pragma unroll
    for (int r = 0; r < 4; ++r) {
        g_ws[WS_XP + (bl0 + r) * 128 + t] = accs[r];
        float sp = accs[r] * asr;
        float sd = accs[r] * adt;
        #pragma unroll
        for (int st = 1; st < 16; st <<= 1) {
            sp += __shfl_xor(sp, st);
            sd += __shfl_xor(sd, st);
        }
        if ((t & 15) == 0) {
            g_ws[WS_XJ + (bl0 + r) * 8 + (t >> 4)] = sp;
            g_ws[WS_XI + (bl0 + r) * 8 + (t >> 4)] = sd;
        }
    }
}

// ---------------------------------------------------------------- gat_main: 4 i/block, all f32
__global__ __launch_bounds__(256) void gat_main(
        const int* __restrict__ adj, const float* __restrict__ ffn_b,
        const float* __restrict__ ln_g, const float* __restrict__ ln_b,
        float* __restrict__ out) {
    __shared__ float s_lds[4][NL * 9];       // 14.4 KB, stride 9 (conflict-free)
    __shared__ float partL[2][4][128];       // 4 KB
    __shared__ float rowL[4][128];           // 2 KB
    __shared__ float hvalL[4][128];          // 2 KB
    __shared__ float inv[4][8];
    __shared__ float mr[4][2];

    int blk = blockIdx.x;
    int b = blk / 25, i0 = (blk % 25) * 4;
    int t = threadIdx.x;
    const float* xp = g_ws + WS_XP;

    // phase 1: scores for 4 i
    {
        int h = t & 7, jj = t >> 3;
        #pragma unroll
        for (int ii = 0; ii < 4; ++ii) {
            int bi = b * NL + i0 + ii;
            float xiv = g_ws[WS_XI + bi * 8 + h];
            #pragma unroll
            for (int r = 0; r < 4; ++r) {
                int j = jj + r * 32;
                if (j < NL) {
                    float s = xiv + g_ws[WS_XJ + (b * NL + j) * 8 + h]
                            + g_ws[WS_ES + ((long)bi * NL + j) * 8 + h];
                    s = s > 0.f ? s : 0.2f * s;
                    s = adj[bi * NL + j] ? s : -1e9f;
                    s_lds[ii][j * 9 + h] = s;
                }
            }
        }
    }
    __syncthreads();
    // phase 2: softmax over j per (ii,h)
    {
        int h = t >> 5, jt = t & 31;
        const float LOG2E = 1.44269504f;
        #pragma unroll
        for (int ii = 0; ii < 4; ++ii) {
            float* sl = s_lds[ii];
            float v0 = sl[jt * 9 + h];
            float v1 = sl[(jt + 32) * 9 + h];
            float v2 = sl[(jt + 64) * 9 + h];
            float v3 = (jt < 4) ? sl[(jt + 96) * 9 + h] : -3.0e38f;
            float m = fmaxf(fmaxf(v0, v1), fmaxf(v2, v3));
            #pragma unroll
            for (int st = 1; st < 32; st <<= 1) m = fmaxf(m, __shfl_xor(m, st));
            float p0 = exp2f((v0 - m) * LOG2E);
            float p1 = exp2f((v1 - m) * LOG2E);
            float p2 = exp2f((v2 - m) * LOG2E);
            float p3 = (jt < 4) ? exp2f((v3 - m) * LOG2E) : 0.f;
            float sum = p0 + p1 + p2 + p3;
            #pragma unroll
            for (int st = 1; st < 32; st <<= 1) sum += __shfl_xor(sum, st);
            sl[jt * 9 + h] = p0;
            sl[(jt + 32) * 9 + h] = p1;
            sl[(jt + 64) * 9 + h] = p2;
            if (jt < 4) sl[(jt + 96) * 9 + h] = p3;
            if (jt == 0) inv[ii][h] = 1.0f / sum;
        }
    }
    __syncthreads();
    // phase 3: aggregation — one xp read serves 4 i
    {
        int d = t & 127, half = t >> 7, hh = d >> 4;
        float a0 = 0.f, a1 = 0.f, a2 = 0.f, a3 = 0.f;
        int j0 = half * 50;
        #pragma unroll 5
        for (int k = 0; k < 50; ++k) {
            int j = j0 + k;
            float xv = xp[(b * NL + j) * 128 + d];
            a0 = fmaf(s_lds[0][j * 9 + hh], xv, a0);
            a1 = fmaf(s_lds[1][j * 9 + hh], xv, a1);
            a2 = fmaf(s_lds[2][j * 9 + hh], xv, a2);
            a3 = fmaf(s_lds[3][j * 9 + hh], xv, a3);
        }
        partL[half][0][d] = a0; partL[half][1][d] = a1;
        partL[half][2][d] = a2; partL[half][3][d] = a3;
    }
    __syncthreads();
    {
        int d = t & 127, g2 = t >> 7;
        #pragma unroll
        for (int g = 0; g < 2; ++g) {
            int ii = g2 * 2 + g;
            rowL[ii][d] = (partL[0][ii][d] + partL[1][ii][d]) * inv[ii][d >> 4];
        }
    }
    __syncthreads();
    // phase 4: FFN — one WfT read serves 4 rows
    {
        int d = t & 127, half = t >> 7;
        const float* WfT = g_ws + WS_WFT;
        float a0 = 0.f, a1 = 0.f, a2 = 0.f, a3 = 0.f;
        int k0 = half * 64;
        #pragma unroll 8
        for (int k = k0; k < k0 + 64; ++k) {
            float wv = WfT[k * 128 + d];
            a0 = fmaf(wv, rowL[0][k], a0);
            a1 = fmaf(wv, rowL[1][k], a1);
            a2 = fmaf(wv, rowL[2][k], a2);
            a3 = fmaf(wv, rowL[3][k], a3);
        }
        partL[half][0][d] = a0; partL[half][1][d] = a1;
        partL[half][2][d] = a2; partL[half][3][d] = a3;
    }
    __syncthreads();
    {
        int d = t & 127, g2 = t >> 7;
        float fb = ffn_b[d];
        #pragma unroll
        for (int g = 0; g < 2; ++g) {
            int ii = g2 * 2 + g;
            hvalL[ii][d] = partL[0][ii][d] + partL[1][ii][d] + fb;
        }
    }
    __syncthreads();
    // phase 5: LayerNorm stats — wave w -> row w (4 waves, 4 rows)
    {
        int wv = t >> 6, lane = t & 63;
        float a = hvalL[wv][lane], b2 = hvalL[wv][lane + 64];
        float s1 = a + b2, s2 = a * a + b2 * b2;
        #pragma unroll
        for (int st = 1; st < 64; st <<= 1) {
            s1 += __shfl_xor(s1, st);
            s2 += __shfl_xor(s2, st);
        }
        if (lane == 0) {
            float mu = s1 * (1.0f / 128.0f);
            float var = s2 * (1.0f / 128.0f) - mu * mu;
            mr[wv][0] = mu;
            mr[wv][1] = rsqrtf(var + 1e-5f);
        }
    }
    __syncthreads();
    {
        int d = t & 127, g2 = t >> 7;
        float lg = ln_g[d], lb = ln_b[d];
        #pragma unroll
        for (int g = 0; g < 2; ++g) {
            int ii = g2 * 2 + g;
            float y = (hvalL[ii][d] - mr[ii][0]) * mr[ii][1] * lg + lb;
            out[(b * NL + i0 + ii) * 128 + d] = fmaxf(y, 0.f);
        }
    }
}

// ---------------------------------------------------------------- launch
extern "C" void kernel_launch(void* const* d_in, const int* in_sizes, int n_in,
                              void* d_out, int out_size, void* d_ws, size_t ws_size,
                              hipStream_t stream) {
    const float* x       = (const float*)d_in[0];
    const int*   adj     = (const int*)  d_in[1];
    const float* e       = (const float*)d_in[2];
    const float* Wx      = (const float*)d_in[3];
    const float* We      = (const float*)d_in[4];
    const float* att_src = (const float*)d_in[5];
    const float* att_dst = (const float*)d_in[6];
    const float* att_e   = (const float*)d_in[7];
    const float* ffn_w   = (const float*)d_in[8];
    const float* ffn_b   = (const float*)d_in[9];
    const float* ln_g    = (const float*)d_in[10];
    const float* ln_b    = (const float*)d_in[11];
    float* out = (float*)d_out;

    hipLaunchKernelGGL(prep_kernel, dim3(66), dim3(256), 0, stream,
                       Wx, We, att_e, ffn_w);
    hipLaunchKernelGGL(escore_kernel, dim3(2048), dim3(256), 0, stream, e);
    hipLaunchKernelGGL(xproj_kernel, dim3(NB * NL / 4), dim3(128), 0, stream,
                       x, att_src, att_dst);
    hipLaunchKernelGGL(gat_main, dim3(NB * 25), dim3(256), 0, stream,
                       adj, ffn_b, ln_g, ln_b, out);
}

// Round 8
// 188.850 us; speedup vs baseline: 1.0305x; 1.0305x over previous
//
#include <hip/hip_runtime.h>
#include <hip/hip_bf16.h>

#define NB 32
#define NL 100
#define ND 128
#define NH 8
#define NE 64
#define NC 16

// scratch layout (float offsets into g_ws) — round-3 proven layout
#define WS_WXT  0        // 128*128 transposed Wx
#define WS_WFT  16384    // 128*128 transposed ffn_w
#define WS_PROJ 32768    // 8*64 combined att_e @ We
#define WS_XI   33280    // B*L*H dest scores
#define WS_XJ   58880    // B*L*H src scores
#define WS_XP   84480    // B*L*128 projected x (f32)
#define WS_ES   (84480 + NB * NL * ND)          // B*L*L*H edge scores
#define WS_TOT  (WS_ES + NB * NL * NL * NH)

__device__ float g_ws[WS_TOT];

static __device__ __forceinline__ float pick8(const float* a, int c) {
    return (c < 4)
        ? ((c < 2) ? (c == 0 ? a[0] : a[1]) : (c == 2 ? a[2] : a[3]))
        : ((c < 6) ? (c == 4 ? a[4] : a[5]) : (c == 6 ? a[6] : a[7]));
}

// ---------------------------------------------------------------- prep (round-3 exact)
__global__ __launch_bounds__(256) void prep_kernel(
        const float* __restrict__ Wx, const float* __restrict__ We,
        const float* __restrict__ att_e, const float* __restrict__ ffn_w) {
    int gid = blockIdx.x * 256 + threadIdx.x;
    if (gid < 16384) {
        int k = gid >> 7, d = gid & 127;
        g_ws[WS_WXT + gid] = Wx[d * 128 + k];
        g_ws[WS_WFT + gid] = ffn_w[d * 128 + k];
    } else if (gid < 16384 + 512) {
        int pid = gid - 16384;
        int h = pid >> 6, eix = pid & 63;
        float acc = 0.f;
        #pragma unroll
        for (int c = 0; c < NC; ++c)
            acc += att_e[h * NC + c] * We[(h * NC + c) * NE + eix];
        g_ws[WS_PROJ + pid] = acc;
    }
}

// ---------------------------------------------------------------- escore (round-3 exact: 5.67 TB/s measured)
__global__ __launch_bounds__(256) void escore_kernel(const float* __restrict__ e) {
    const float4* proj4 = (const float4*)(g_ws + WS_PROJ);
    int t = threadIdx.x;
    int lane = t & 63;
    int j_sub = lane >> 3, c_sub = lane & 7;
    float4 p4[16];
    #pragma unroll
    for (int h = 0; h < 8; ++h) {
        p4[h * 2]     = proj4[h * 16 + c_sub * 2];
        p4[h * 2 + 1] = proj4[h * 16 + c_sub * 2 + 1];
    }
    const float4* e4 = (const float4*)e;
    int wid = blockIdx.x * 4 + (t >> 6);
    int nw = gridDim.x * 4;
    for (int chunk = wid; chunk < NB * NL * NL / 8; chunk += nw) {
        long rid = (long)chunk * 8 + j_sub;
        float4 ev0 = e4[rid * 16 + c_sub * 2];
        float4 ev1 = e4[rid * 16 + c_sub * 2 + 1];
        float part[8];
        #pragma unroll
        for (int h = 0; h < 8; ++h) {
            float4 a = p4[h * 2], bq = p4[h * 2 + 1];
            part[h] = ev0.x * a.x + ev0.y * a.y + ev0.z * a.z + ev0.w * a.w
                    + ev1.x * bq.x + ev1.y * bq.y + ev1.z * bq.z + ev1.w * bq.w;
        }
        #pragma unroll
        for (int st = 1; st < 8; st <<= 1)
            #pragma unroll
            for (int h = 0; h < 8; ++h)
                part[h] += __shfl_xor(part[h], st);
        g_ws[WS_ES + rid * 8 + c_sub] = pick8(part, c_sub);
    }
}

// ---------------------------------------------------------------- xproj: 4 rows/block (round-5 proven)
__global__ __launch_bounds__(128) void xproj_kernel(
        const float* __restrict__ x,
        const float* __restrict__ att_src, const float* __restrict__ att_dst) {
    __shared__ float xrowL[4][128];
    int bl0 = blockIdx.x * 4;
    int t = threadIdx.x;
    #pragma unroll
    for (int r = 0; r < 4; ++r)
        xrowL[r][t] = x[(bl0 + r) * 128 + t];
    __syncthreads();
    const float* WxT = g_ws + WS_WXT;
    float acc0 = 0.f, acc1 = 0.f, acc2 = 0.f, acc3 = 0.f;
    #pragma unroll 8
    for (int k = 0; k < 128; ++k) {
        float wv = WxT[k * 128 + t];
        acc0 = fmaf(xrowL[0][k], wv, acc0);
        acc1 = fmaf(xrowL[1][k], wv, acc1);
        acc2 = fmaf(xrowL[2][k], wv, acc2);
        acc3 = fmaf(xrowL[3][k], wv, acc3);
    }
    float accs[4] = {acc0, acc1, acc2, acc3};
    float asr = att_src[t], adt = att_dst[t];
    #pragma unroll
    for (int r = 0; r < 4; ++r) {
        g_ws[WS_XP + (bl0 + r) * 128 + t] = accs[r];
        float sp = accs[r] * asr;
        float sd = accs[r] * adt;
        #pragma unroll
        for (int st = 1; st < 16; st <<= 1) {
            sp += __shfl_xor(sp, st);
            sd += __shfl_xor(sd, st);
        }
        if ((t & 15) == 0) {
            g_ws[WS_XJ + (bl0 + r) * 8 + (t >> 4)] = sp;
            g_ws[WS_XI + (bl0 + r) * 8 + (t >> 4)] = sd;
        }
    }
}

// ---------------------------------------------------------------- gat_main: 2 i/block, all f32 (round-5 proven)
__global__ __launch_bounds__(256) void gat_main(
        const int* __restrict__ adj, const float* __restrict__ ffn_b,
        const float* __restrict__ ln_g, const float* __restrict__ ln_b,
        float* __restrict__ out) {
    __shared__ float s_lds[2][NL * 9];       // scores/alpha, stride 9 (conflict-free)
    __shared__ float partL[2][2][128];
    __shared__ float rowL[2][128];
    __shared__ float hvalL[2][128];
    __shared__ float inv[2][8];
    __shared__ float mr[2][2];

    int blk = blockIdx.x;
    int b = blk / 50, i0 = (blk % 50) * 2;
    int t = threadIdx.x;
    const float* xp = g_ws + WS_XP;

    // phase 1: scores for 2 i
    {
        int h = t & 7, jj = t >> 3;
        #pragma unroll
        for (int ii = 0; ii < 2; ++ii) {
            int bi = b * NL + i0 + ii;
            float xiv = g_ws[WS_XI + bi * 8 + h];
            #pragma unroll
            for (int r = 0; r < 4; ++r) {
                int j = jj + r * 32;
                if (j < NL) {
                    float s = xiv + g_ws[WS_XJ + (b * NL + j) * 8 + h]
                            + g_ws[WS_ES + ((long)bi * NL + j) * 8 + h];
                    s = s > 0.f ? s : 0.2f * s;
                    s = adj[bi * NL + j] ? s : -1e9f;
                    s_lds[ii][j * 9 + h] = s;
                }
            }
        }
    }
    __syncthreads();
    // phase 2: softmax over j per (ii,h)
    {
        int h = t >> 5, jt = t & 31;
        const float LOG2E = 1.44269504f;
        #pragma unroll
        for (int ii = 0; ii < 2; ++ii) {
            float* sl = s_lds[ii];
            float v0 = sl[jt * 9 + h];
            float v1 = sl[(jt + 32) * 9 + h];
            float v2 = sl[(jt + 64) * 9 + h];
            float v3 = (jt < 4) ? sl[(jt + 96) * 9 + h] : -3.0e38f;
            float m = fmaxf(fmaxf(v0, v1), fmaxf(v2, v3));
            #pragma unroll
            for (int st = 1; st < 32; st <<= 1) m = fmaxf(m, __shfl_xor(m, st));
            float p0 = exp2f((v0 - m) * LOG2E);
            float p1 = exp2f((v1 - m) * LOG2E);
            float p2 = exp2f((v2 - m) * LOG2E);
            float p3 = (jt < 4) ? exp2f((v3 - m) * LOG2E) : 0.f;
            float sum = p0 + p1 + p2 + p3;
            #pragma unroll
            for (int st = 1; st < 32; st <<= 1) sum += __shfl_xor(sum, st);
            sl[jt * 9 + h] = p0;
            sl[(jt + 32) * 9 + h] = p1;
            sl[(jt + 64) * 9 + h] = p2;
            if (jt < 4) sl[(jt + 96) * 9 + h] = p3;
            if (jt == 0) inv[ii][h] = 1.0f / sum;
        }
    }
    __syncthreads();
    // phase 3: aggregation — one xp read serves 2 i
    {
        int d = t & 127, half = t >> 7, hh = d >> 4;
        float a0 = 0.f, a1 = 0.f;
        int j0 = half * 50;
        #pragma unroll 5
        for (int k = 0; k < 50; ++k) {
            int j = j0 + k;
            float xv = xp[(b * NL + j) * 128 + d];
            a0 = fmaf(s_lds[0][j * 9 + hh], xv, a0);
            a1 = fmaf(s_lds[1][j * 9 + hh], xv, a1);
        }
        partL[half][0][d] = a0;
        partL[half][1][d] = a1;
    }
    __syncthreads();
    {
        int d = t & 127, ii = t >> 7;
        rowL[ii][d] = (partL[0][ii][d] + partL[1][ii][d]) * inv[ii][d >> 4];
    }
    __syncthreads();
    // phase 4: FFN — one WfT read serves 2 rows
    {
        int d = t & 127, half = t >> 7;
        const float* WfT = g_ws + WS_WFT;
        float a0 = 0.f, a1 = 0.f;
        int k0 = half * 64;
        #pragma unroll 8
        for (int k = k0; k < k0 + 64; ++k) {
            float wv = WfT[k * 128 + d];
            a0 = fmaf(wv, rowL[0][k], a0);
            a1 = fmaf(wv, rowL[1][k], a1);
        }
        partL[half][0][d] = a0;
        partL[half][1][d] = a1;
    }
    __syncthreads();
    {
        int d = t & 127, ii = t >> 7;
        hvalL[ii][d] = partL[0][ii][d] + partL[1][ii][d] + ffn_b[d];
    }
    __syncthreads();
    // phase 5: LayerNorm stats — wave 0 -> row 0, wave 1 -> row 1
    {
        int row = t >> 6, lane = t & 63;
        if (row < 2) {
            float a = hvalL[row][lane], b2 = hvalL[row][lane + 64];
            float s1 = a + b2, s2 = a * a + b2 * b2;
            #pragma unroll
            for (int st = 1; st < 64; st <<= 1) {
                s1 += __shfl_xor(s1, st);
                s2 += __shfl_xor(s2, st);
            }
            if (lane == 0) {
                float mu = s1 * (1.0f / 128.0f);
                float var = s2 * (1.0f / 128.0f) - mu * mu;
                mr[row][0] = mu;
                mr[row][1] = rsqrtf(var + 1e-5f);
            }
        }
    }
    __syncthreads();
    {
        int d = t & 127, ii = t >> 7;
        float y = (hvalL[ii][d] - mr[ii][0]) * mr[ii][1] * ln_g[d] + ln_b[d];
        out[(b * NL + i0 + ii) * 128 + d] = fmaxf(y, 0.f);
    }
}

// ---------------------------------------------------------------- launch
extern "C" void kernel_launch(void* const* d_in, const int* in_sizes, int n_in,
                              void* d_out, int out_size, void* d_ws, size_t ws_size,
                              hipStream_t stream) {
    const float* x       = (const float*)d_in[0];
    const int*   adj     = (const int*)  d_in[1];
    const float* e       = (const float*)d_in[2];
    const float* Wx      = (const float*)d_in[3];
    const float* We      = (const float*)d_in[4];
    const float* att_src = (const float*)d_in[5];
    const float* att_dst = (const float*)d_in[6];
    const float* att_e   = (const float*)d_in[7];
    const float* ffn_w   = (const float*)d_in[8];
    const float* ffn_b   = (const float*)d_in[9];
    const float* ln_g    = (const float*)d_in[10];
    const float* ln_b    = (const float*)d_in[11];
    float* out = (float*)d_out;

    hipLaunchKernelGGL(prep_kernel, dim3(66), dim3(256), 0, stream,
                       Wx, We, att_e, ffn_w);
    hipLaunchKernelGGL(escore_kernel, dim3(2048), dim3(256), 0, stream, e);
    hipLaunchKernelGGL(xproj_kernel, dim3(NB * NL / 4), dim3(128), 0, stream,
                       x, att_src, att_dst);
    hipLaunchKernelGGL(gat_main, dim3(NB * 50), dim3(256), 0, stream,
                       adj, ffn_b, ln_g, ln_b, out);
}

// Round 9
// 180.283 us; speedup vs baseline: 1.0795x; 1.0475x over previous
//
#include <hip/hip_runtime.h>
#include <hip/hip_bf16.h>

#define NB 32
#define NL 100
#define ND 128
#define NH 8
#define NE 64
#define NC 16

// scratch layout (float offsets into g_ws) — round-3 proven layout
#define WS_WXT  0        // 128*128 transposed Wx
#define WS_WFT  16384    // 128*128 transposed ffn_w
#define WS_PROJ 32768    // 8*64 combined att_e @ We
#define WS_XI   33280    // B*L*H dest scores
#define WS_XJ   58880    // B*L*H src scores
#define WS_XP   84480    // B*L*128 projected x (f32)
#define WS_ES   (84480 + NB * NL * ND)          // B*L*L*H edge scores
#define WS_TOT  (WS_ES + NB * NL * NL * NH)

__device__ float g_ws[WS_TOT];

static __device__ __forceinline__ float pick8(const float* a, int c) {
    return (c < 4)
        ? ((c < 2) ? (c == 0 ? a[0] : a[1]) : (c == 2 ? a[2] : a[3]))
        : ((c < 6) ? (c == 4 ? a[4] : a[5]) : (c == 6 ? a[6] : a[7]));
}

// ---------------------------------------------------------------- prep (round-3 exact)
__global__ __launch_bounds__(256) void prep_kernel(
        const float* __restrict__ Wx, const float* __restrict__ We,
        const float* __restrict__ att_e, const float* __restrict__ ffn_w) {
    int gid = blockIdx.x * 256 + threadIdx.x;
    if (gid < 16384) {
        int k = gid >> 7, d = gid & 127;
        g_ws[WS_WXT + gid] = Wx[d * 128 + k];
        g_ws[WS_WFT + gid] = ffn_w[d * 128 + k];
    } else if (gid < 16384 + 512) {
        int pid = gid - 16384;
        int h = pid >> 6, eix = pid & 63;
        float acc = 0.f;
        #pragma unroll
        for (int c = 0; c < NC; ++c)
            acc += att_e[h * NC + c] * We[(h * NC + c) * NE + eix];
        g_ws[WS_PROJ + pid] = acc;
    }
}

// ---------------------------------------------------------------- merged escore + xproj
// blocks [0,400): xproj (8 rows each, two independent 128-thread halves running
//                 the round-5-proven 4-row code)
// blocks [400,2448): escore (round-3-proven stripe, eblk = blk-400, nw = 8192)
// xproj blocks lead the grid so their ~4 µs of L2-bound work hides under
// escore's 17 µs HBM stream.
__global__ __launch_bounds__(256) void mega2_kernel(
        const float* __restrict__ x, const float* __restrict__ e,
        const float* __restrict__ att_src, const float* __restrict__ att_dst) {
    __shared__ float xrowL[8][128];
    int blk = blockIdx.x;
    int t = threadIdx.x;

    if (blk < 400) {
        // ---------------- xproj branch ----------------
        int hb = t >> 7;             // half 0/1
        int tl = t & 127;
        int bl0 = blk * 8 + hb * 4;  // 4 rows per half
        #pragma unroll
        for (int r = 0; r < 4; ++r)
            xrowL[hb * 4 + r][tl] = x[(bl0 + r) * 128 + tl];
        __syncthreads();
        const float* WxT = g_ws + WS_WXT;
        float acc0 = 0.f, acc1 = 0.f, acc2 = 0.f, acc3 = 0.f;
        #pragma unroll 8
        for (int k = 0; k < 128; ++k) {
            float wv = WxT[k * 128 + tl];
            acc0 = fmaf(xrowL[hb * 4 + 0][k], wv, acc0);
            acc1 = fmaf(xrowL[hb * 4 + 1][k], wv, acc1);
            acc2 = fmaf(xrowL[hb * 4 + 2][k], wv, acc2);
            acc3 = fmaf(xrowL[hb * 4 + 3][k], wv, acc3);
        }
        float accs[4] = {acc0, acc1, acc2, acc3};
        float asr = att_src[tl], adt = att_dst[tl];
        #pragma unroll
        for (int r = 0; r < 4; ++r) {
            g_ws[WS_XP + (bl0 + r) * 128 + tl] = accs[r];
            float sp = accs[r] * asr;
            float sd = accs[r] * adt;
            #pragma unroll
            for (int st = 1; st < 16; st <<= 1) {
                sp += __shfl_xor(sp, st);
                sd += __shfl_xor(sd, st);
            }
            if ((tl & 15) == 0) {
                g_ws[WS_XJ + (bl0 + r) * 8 + (tl >> 4)] = sp;
                g_ws[WS_XI + (bl0 + r) * 8 + (tl >> 4)] = sd;
            }
        }
    } else {
        // ---------------- escore branch (round-3 exact math/stripe) ----------------
        const float4* proj4 = (const float4*)(g_ws + WS_PROJ);
        int lane = t & 63;
        int j_sub = lane >> 3, c_sub = lane & 7;
        float4 p4[16];
        #pragma unroll
        for (int h = 0; h < 8; ++h) {
            p4[h * 2]     = proj4[h * 16 + c_sub * 2];
            p4[h * 2 + 1] = proj4[h * 16 + c_sub * 2 + 1];
        }
        const float4* e4 = (const float4*)e;
        int wid = (blk - 400) * 4 + (t >> 6);
        const int nw = 2048 * 4;
        for (int chunk = wid; chunk < NB * NL * NL / 8; chunk += nw) {
            long rid = (long)chunk * 8 + j_sub;
            float4 ev0 = e4[rid * 16 + c_sub * 2];
            float4 ev1 = e4[rid * 16 + c_sub * 2 + 1];
            float part[8];
            #pragma unroll
            for (int h = 0; h < 8; ++h) {
                float4 a = p4[h * 2], bq = p4[h * 2 + 1];
                part[h] = ev0.x * a.x + ev0.y * a.y + ev0.z * a.z + ev0.w * a.w
                        + ev1.x * bq.x + ev1.y * bq.y + ev1.z * bq.z + ev1.w * bq.w;
            }
            #pragma unroll
            for (int st = 1; st < 8; st <<= 1)
                #pragma unroll
                for (int h = 0; h < 8; ++h)
                    part[h] += __shfl_xor(part[h], st);
            g_ws[WS_ES + rid * 8 + c_sub] = pick8(part, c_sub);
        }
    }
}

// ---------------------------------------------------------------- gat_main: 2 i/block, all f32 (round-5 proven)
__global__ __launch_bounds__(256) void gat_main(
        const int* __restrict__ adj, const float* __restrict__ ffn_b,
        const float* __restrict__ ln_g, const float* __restrict__ ln_b,
        float* __restrict__ out) {
    __shared__ float s_lds[2][NL * 9];       // scores/alpha, stride 9 (conflict-free)
    __shared__ float partL[2][2][128];
    __shared__ float rowL[2][128];
    __shared__ float hvalL[2][128];
    __shared__ float inv[2][8];
    __shared__ float mr[2][2];

    int blk = blockIdx.x;
    int b = blk / 50, i0 = (blk % 50) * 2;
    int t = threadIdx.x;
    const float* xp = g_ws + WS_XP;

    // phase 1: scores for 2 i
    {
        int h = t & 7, jj = t >> 3;
        #pragma unroll
        for (int ii = 0; ii < 2; ++ii) {
            int bi = b * NL + i0 + ii;
            float xiv = g_ws[WS_XI + bi * 8 + h];
            #pragma unroll
            for (int r = 0; r < 4; ++r) {
                int j = jj + r * 32;
                if (j < NL) {
                    float s = xiv + g_ws[WS_XJ + (b * NL + j) * 8 + h]
                            + g_ws[WS_ES + ((long)bi * NL + j) * 8 + h];
                    s = s > 0.f ? s : 0.2f * s;
                    s = adj[bi * NL + j] ? s : -1e9f;
                    s_lds[ii][j * 9 + h] = s;
                }
            }
        }
    }
    __syncthreads();
    // phase 2: softmax over j per (ii,h)
    {
        int h = t >> 5, jt = t & 31;
        const float LOG2E = 1.44269504f;
        #pragma unroll
        for (int ii = 0; ii < 2; ++ii) {
            float* sl = s_lds[ii];
            float v0 = sl[jt * 9 + h];
            float v1 = sl[(jt + 32) * 9 + h];
            float v2 = sl[(jt + 64) * 9 + h];
            float v3 = (jt < 4) ? sl[(jt + 96) * 9 + h] : -3.0e38f;
            float m = fmaxf(fmaxf(v0, v1), fmaxf(v2, v3));
            #pragma unroll
            for (int st = 1; st < 32; st <<= 1) m = fmaxf(m, __shfl_xor(m, st));
            float p0 = exp2f((v0 - m) * LOG2E);
            float p1 = exp2f((v1 - m) * LOG2E);
            float p2 = exp2f((v2 - m) * LOG2E);
            float p3 = (jt < 4) ? exp2f((v3 - m) * LOG2E) : 0.f;
            float sum = p0 + p1 + p2 + p3;
            #pragma unroll
            for (int st = 1; st < 32; st <<= 1) sum += __shfl_xor(sum, st);
            sl[jt * 9 + h] = p0;
            sl[(jt + 32) * 9 + h] = p1;
            sl[(jt + 64) * 9 + h] = p2;
            if (jt < 4) sl[(jt + 96) * 9 + h] = p3;
            if (jt == 0) inv[ii][h] = 1.0f / sum;
        }
    }
    __syncthreads();
    // phase 3: aggregation — one xp read serves 2 i
    {
        int d = t & 127, half = t >> 7, hh = d >> 4;
        float a0 = 0.f, a1 = 0.f;
        int j0 = half * 50;
        #pragma unroll 5
        for (int k = 0; k < 50; ++k) {
            int j = j0 + k;
            float xv = xp[(b * NL + j) * 128 + d];
            a0 = fmaf(s_lds[0][j * 9 + hh], xv, a0);
            a1 = fmaf(s_lds[1][j * 9 + hh], xv, a1);
        }
        partL[half][0][d] = a0;
        partL[half][1][d] = a1;
    }
    __syncthreads();
    {
        int d = t & 127, ii = t >> 7;
        rowL[ii][d] = (partL[0][ii][d] + partL[1][ii][d]) * inv[ii][d >> 4];
    }
    __syncthreads();
    // phase 4: FFN — one WfT read serves 2 rows
    {
        int d = t & 127, half = t >> 7;
        const float* WfT = g_ws + WS_WFT;
        float a0 = 0.f, a1 = 0.f;
        int k0 = half * 64;
        #pragma unroll 8
        for (int k = k0; k < k0 + 64; ++k) {
            float wv = WfT[k * 128 + d];
            a0 = fmaf(wv, rowL[0][k], a0);
            a1 = fmaf(wv, rowL[1][k], a1);
        }
        partL[half][0][d] = a0;
        partL[half][1][d] = a1;
    }
    __syncthreads();
    {
        int d = t & 127, ii = t >> 7;
        hvalL[ii][d] = partL[0][ii][d] + partL[1][ii][d] + ffn_b[d];
    }
    __syncthreads();
    // phase 5: LayerNorm stats — wave 0 -> row 0, wave 1 -> row 1
    {
        int row = t >> 6, lane = t & 63;
        if (row < 2) {
            float a = hvalL[row][lane], b2 = hvalL[row][lane + 64];
            float s1 = a + b2, s2 = a * a + b2 * b2;
            #pragma unroll
            for (int st = 1; st < 64; st <<= 1) {
                s1 += __shfl_xor(s1, st);
                s2 += __shfl_xor(s2, st);
            }
            if (lane == 0) {
                float mu = s1 * (1.0f / 128.0f);
                float var = s2 * (1.0f / 128.0f) - mu * mu;
                mr[row][0] = mu;
                mr[row][1] = rsqrtf(var + 1e-5f);
            }
        }
    }
    __syncthreads();
    {
        int d = t & 127, ii = t >> 7;
        float y = (hvalL[ii][d] - mr[ii][0]) * mr[ii][1] * ln_g[d] + ln_b[d];
        out[(b * NL + i0 + ii) * 128 + d] = fmaxf(y, 0.f);
    }
}

// ---------------------------------------------------------------- launch
extern "C" void kernel_launch(void* const* d_in, const int* in_sizes, int n_in,
                              void* d_out, int out_size, void* d_ws, size_t ws_size,
                              hipStream_t stream) {
    const float* x       = (const float*)d_in[0];
    const int*   adj     = (const int*)  d_in[1];
    const float* e       = (const float*)d_in[2];
    const float* Wx      = (const float*)d_in[3];
    const float* We      = (const float*)d_in[4];
    const float* att_src = (const float*)d_in[5];
    const float* att_dst = (const float*)d_in[6];
    const float* att_e   = (const float*)d_in[7];
    const float* ffn_w   = (const float*)d_in[8];
    const float* ffn_b   = (const float*)d_in[9];
    const float* ln_g    = (const float*)d_in[10];
    const float* ln_b    = (const float*)d_in[11];
    float* out = (float*)d_out;

    hipLaunchKernelGGL(prep_kernel, dim3(66), dim3(256), 0, stream,
                       Wx, We, att_e, ffn_w);
    hipLaunchKernelGGL(mega2_kernel, dim3(2448), dim3(256), 0, stream,
                       x, e, att_src, att_dst);
    hipLaunchKernelGGL(gat_main, dim3(NB * 50), dim3(256), 0, stream,
                       adj, ffn_b, ln_g, ln_b, out);
}